// Round 14
// baseline (280.911 us; speedup 1.0000x reference)
//
#include <hip/hip_runtime.h>

#define HH 128
#define GG 256
#define CAP 32
#define PSPLIT 16

using f32x4  = __attribute__((ext_vector_type(4))) float;
using bf16x4 = __attribute__((ext_vector_type(4))) __bf16;
using bf16x8 = __attribute__((ext_vector_type(8))) __bf16;

static __device__ __forceinline__ float bf2f(unsigned int u) {
    unsigned int x = u << 16;
    return __builtin_bit_cast(float, x);
}
static __device__ __forceinline__ unsigned short f2bf(float f) {
    __bf16 b = (__bf16)f;
    return __builtin_bit_cast(unsigned short, b);
}

// --------------------------------------------- prep: zero + packW x5 + bound
__global__ __launch_bounds__(256) void prep_k(
    int* __restrict__ cnt, float* __restrict__ pooled, int n,
    const float* __restrict__ Wa, const float* __restrict__ Wb,
    const float* __restrict__ Wc, const float* __restrict__ Wd,
    const float* __restrict__ We, __bf16* __restrict__ Wp,
    const int* __restrict__ batch, int* __restrict__ bound, int zb)
{
    const int t = threadIdx.x, b = blockIdx.x;
    if (b < zb) {
        const int i = b * 256 + t;
        if (i < n) cnt[i] = 0;
        if (i < GG * HH) pooled[i] = 0.f;
    } else if (b < zb + 40) {
        const int which = b - zb;
        const int mat = which >> 3;
        const float* W = (mat == 0) ? Wa : (mat == 1) ? Wb : (mat == 2) ? Wc
                       : (mat == 3) ? Wd : We;
        const int slot = (which & 7) * 256 + t;
        const int frag = slot >> 6, lane = slot & 63;
        const int mb = frag >> 2, kb = frag & 3;
        const int col = mb * 16 + (lane & 15);
        const int k0  = kb * 32 + (lane >> 4) * 8;
        bf16x8 v;
        #pragma unroll
        for (int j = 0; j < 8; ++j) v[j] = (__bf16)W[(k0 + j) * HH + col];
        *(bf16x8*)&Wp[(size_t)mat * 16384 + slot * 8] = v;
    } else {
        const int g = t;
        int lo = 0, hi = n;
        while (lo < hi) { int m = (lo + hi) >> 1; if (batch[m] < g) lo = m + 1; else hi = m; }
        bound[g] = lo;
        if (g == 0) bound[GG] = n;
    }
}

// ------------------------------------- bucket-CSR build (single pass)
__global__ __launch_bounds__(256) void fill_k(const int* __restrict__ src,
                                              const int* __restrict__ dst,
                                              int* __restrict__ cnt,
                                              int* __restrict__ slotbuf, int ne)
{
    int e = blockIdx.x * 256 + threadIdx.x;
    if (e < ne) {
        const int d = dst[e];
        const int off = atomicAdd(&cnt[d], 1);
        if (off < CAP) slotbuf[d * CAP + off] = src[e];
    }
}

// ------------------------------------------------- layer 0 (agg + MLP fused)
__global__ __launch_bounds__(256) void l0_k(
    const float* __restrict__ x,
    const int* __restrict__ cnt, const int* __restrict__ slotbuf,
    const float* __restrict__ W1, const float* __restrict__ b1,
    const __bf16* __restrict__ Wp2, const float* __restrict__ b2,
    unsigned short* __restrict__ hout, int n)
{
    __shared__ __bf16 Wl[16384];                // 32 KB W2^T frags
    __shared__ unsigned short tt[4][4096];      // 8 KB per-wave t-tile
    __shared__ float b1l[HH], b2l[HH], w1l[HH];

    const int t    = threadIdx.x;
    const int lane = t & 63, wv = t >> 6;
    const int l16  = lane & 15, lq = lane >> 4;
    const int r0    = blockIdx.x * 128 + wv * 32;
    const int nodeA = r0 + l16, nodeB = r0 + 16 + l16;
    const int rowA  = min(nodeA, n - 1), rowB = min(nodeB, n - 1);
    const int swz   = (l16 & 7) << 4;

    #pragma unroll
    for (int i = 0; i < 8; ++i)
        *(int4*)&Wl[(i * 256 + t) * 8] = *(const int4*)&Wp2[(i * 256 + t) * 8];
    if (t < HH) { b2l[t] = b2[t]; b1l[t] = b1[t]; w1l[t] = W1[t]; }

    // per-lane scalar aggregation of x (masked 4-unroll, no serial tail)
    float sA, sB;
    {
        float s0 = x[rowA], s1 = 0.f, s2 = 0.f, s3 = 0.f;
        const int dA = min(cnt[rowA], CAP);
        const int* sp = &slotbuf[rowA * CAP];
        for (int j = 0; j < dA; j += 4) {
            const int i1 = min(j + 1, dA - 1), i2 = min(j + 2, dA - 1), i3 = min(j + 3, dA - 1);
            const float v0 = x[sp[j]],  v1 = x[sp[i1]];
            const float v2 = x[sp[i2]], v3 = x[sp[i3]];
            s0 += v0;
            s1 += (j + 1 < dA) ? v1 : 0.f;
            s2 += (j + 2 < dA) ? v2 : 0.f;
            s3 += (j + 3 < dA) ? v3 : 0.f;
        }
        sA = (s0 + s1) + (s2 + s3);
        s0 = x[rowB]; s1 = s2 = s3 = 0.f;
        const int dB = min(cnt[rowB], CAP);
        const int* sq = &slotbuf[rowB * CAP];
        for (int j = 0; j < dB; j += 4) {
            const int i1 = min(j + 1, dB - 1), i2 = min(j + 2, dB - 1), i3 = min(j + 3, dB - 1);
            const float v0 = x[sq[j]],  v1 = x[sq[i1]];
            const float v2 = x[sq[i2]], v3 = x[sq[i3]];
            s0 += v0;
            s1 += (j + 1 < dB) ? v1 : 0.f;
            s2 += (j + 2 < dB) ? v2 : 0.f;
            s3 += (j + 3 < dB) ? v3 : 0.f;
        }
        sB = (s0 + s1) + (s2 + s3);
    }
    __syncthreads();

    char* tl = (char*)tt[wv];
    #pragma unroll
    for (int mt = 0; mt < 8; ++mt) {
        const f32x4 w  = *(const f32x4*)&w1l[mt * 16 + lq * 4];
        const f32x4 bb = *(const f32x4*)&b1l[mt * 16 + lq * 4];
        bf16x4 pa, pb;
        #pragma unroll
        for (int r = 0; r < 4; ++r) {
            pa[r] = (__bf16)fmaxf(fmaf(sA, w[r], bb[r]), 0.f);
            pb[r] = (__bf16)fmaxf(fmaf(sB, w[r], bb[r]), 0.f);
        }
        *(bf16x4*)(tl + ((l16 * 256 + mt * 32 + lq * 8) ^ swz)) = pa;
        *(bf16x4*)(tl + (((16 + l16) * 256 + mt * 32 + lq * 8) ^ swz)) = pb;
    }

    // h^T = W2^T @ t^T (t-tile is wave-private; no barrier needed)
    bf16x8 tfA[4], tfB[4];
    #pragma unroll
    for (int kb = 0; kb < 4; ++kb) {
        tfA[kb] = *(const bf16x8*)(tl + ((l16 * 256 + kb * 64 + lq * 16) ^ swz));
        tfB[kb] = *(const bf16x8*)(tl + (((16 + l16) * 256 + kb * 64 + lq * 16) ^ swz));
    }
    f32x4 a2A[8], a2B[8];
    #pragma unroll
    for (int mb = 0; mb < 8; ++mb) {
        const f32x4 bb = *(const f32x4*)&b2l[mb * 16 + lq * 4];
        a2A[mb] = bb; a2B[mb] = bb;
    }
    #pragma unroll
    for (int mb = 0; mb < 8; ++mb)
        #pragma unroll
        for (int kb = 0; kb < 4; ++kb) {
            const bf16x8 wf = *(const bf16x8*)&Wl[((mb * 4 + kb) * 64 + lane) * 8];
            a2A[mb] = __builtin_amdgcn_mfma_f32_16x16x32_bf16(wf, tfA[kb], a2A[mb], 0, 0, 0);
            a2B[mb] = __builtin_amdgcn_mfma_f32_16x16x32_bf16(wf, tfB[kb], a2B[mb], 0, 0, 0);
        }
    if (nodeA < n) {
        #pragma unroll
        for (int mb = 0; mb < 8; ++mb) {
            bf16x4 p;
            #pragma unroll
            for (int r = 0; r < 4; ++r) p[r] = (__bf16)a2A[mb][r];
            *(bf16x4*)&hout[(size_t)nodeA * HH + mb * 16 + lq * 4] = p;
        }
    }
    if (nodeB < n) {
        #pragma unroll
        for (int mb = 0; mb < 8; ++mb) {
            bf16x4 p;
            #pragma unroll
            for (int r = 0; r < 4; ++r) p[r] = (__bf16)a2B[mb][r];
            *(bf16x4*)&hout[(size_t)nodeB * HH + mb * 16 + lq * 4] = p;
        }
    }
}

// ------------------------------------------- dense pull aggregation (bf16)
static __device__ __forceinline__ void agg_body(
    const unsigned short* __restrict__ h, const int* __restrict__ cnt,
    const int* __restrict__ slotbuf, unsigned short* __restrict__ z, int n)
{
    const int wave = (blockIdx.x * 256 + threadIdx.x) >> 6;
    const int lane = threadIdx.x & 63;
    const int half = lane >> 5, sl = lane & 31;
    const int nw   = (gridDim.x * 256) >> 6;
    const int npairs = (n + 1) >> 1;
    const uint2* h8 = (const uint2*)h;     // 8B = 4 bf16; row = 32 uint2
    uint2* z8 = (uint2*)z;

    for (int pr = wave; pr < npairs; pr += nw) {
        const int node = min(2 * pr + half, n - 1);
        const int deg = min(cnt[node], CAP);
        const int* sp = &slotbuf[node * CAP];
        const uint2 su = h8[(size_t)node * 32 + sl];
        float a0 = bf2f(su.x & 0xffff), a1 = bf2f(su.x >> 16);
        float a2 = bf2f(su.y & 0xffff), a3 = bf2f(su.y >> 16);
        float b0 = 0.f, b1 = 0.f, b2 = 0.f, b3 = 0.f;
        float c0 = 0.f, c1 = 0.f, c2 = 0.f, c3 = 0.f;
        float d0 = 0.f, d1 = 0.f, d2 = 0.f, d3 = 0.f;
        for (int j = 0; j < deg; j += 4) {
            const int i1 = min(j + 1, deg - 1), i2 = min(j + 2, deg - 1), i3 = min(j + 3, deg - 1);
            const uint2 v0 = h8[(size_t)sp[j]  * 32 + sl];
            const uint2 v1 = h8[(size_t)sp[i1] * 32 + sl];
            const uint2 v2 = h8[(size_t)sp[i2] * 32 + sl];
            const uint2 v3 = h8[(size_t)sp[i3] * 32 + sl];
            a0 += bf2f(v0.x & 0xffff); a1 += bf2f(v0.x >> 16);
            a2 += bf2f(v0.y & 0xffff); a3 += bf2f(v0.y >> 16);
            const bool m1 = (j + 1 < deg), m2 = (j + 2 < deg), m3 = (j + 3 < deg);
            b0 += m1 ? bf2f(v1.x & 0xffff) : 0.f; b1 += m1 ? bf2f(v1.x >> 16) : 0.f;
            b2 += m1 ? bf2f(v1.y & 0xffff) : 0.f; b3 += m1 ? bf2f(v1.y >> 16) : 0.f;
            c0 += m2 ? bf2f(v2.x & 0xffff) : 0.f; c1 += m2 ? bf2f(v2.x >> 16) : 0.f;
            c2 += m2 ? bf2f(v2.y & 0xffff) : 0.f; c3 += m2 ? bf2f(v2.y >> 16) : 0.f;
            d0 += m3 ? bf2f(v3.x & 0xffff) : 0.f; d1 += m3 ? bf2f(v3.x >> 16) : 0.f;
            d2 += m3 ? bf2f(v3.y & 0xffff) : 0.f; d3 += m3 ? bf2f(v3.y >> 16) : 0.f;
        }
        const float s0 = (a0 + b0) + (c0 + d0);
        const float s1 = (a1 + b1) + (c1 + d1);
        const float s2 = (a2 + b2) + (c2 + d2);
        const float s3 = (a3 + b3) + (c3 + d3);
        uint2 o;
        o.x = (unsigned int)f2bf(s0) | ((unsigned int)f2bf(s1) << 16);
        o.y = (unsigned int)f2bf(s2) | ((unsigned int)f2bf(s3) << 16);
        z8[(size_t)node * 32 + sl] = o;
    }
}
__global__ __launch_bounds__(256) void agg1_k(const unsigned short* h, const int* cnt,
                                              const int* slotbuf, unsigned short* z, int n)
{ agg_body(h, cnt, slotbuf, z, n); }
__global__ __launch_bounds__(256) void agg2_k(const unsigned short* h, const int* cnt,
                                              const int* slotbuf, unsigned short* z, int n)
{ agg_body(h, cnt, slotbuf, z, n); }

// --------------------------------------------------- fused MLP v3 (pipelined)
// h = relu(z @ W1 + b1) @ W2 + b2, transposed MFMA form.
// 512 threads = 8 waves; W1^T AND W2^T LDS-resident, staged ONCE per block.
// Grid-stride over 256-node tiles with z-prefetch: next tile's z fragments
// are loaded between GEMM1 and GEMM2 so their latency hides under MFMAs.
// ZERO barriers after the W-stage (t-tiles are wave-private; per-wave
// in-order DS pipe orders write->read).
static __device__ __forceinline__ void loadz(
    const unsigned short* __restrict__ z, int rowA, int rowB, int lq,
    bf16x8* zfA, bf16x8* zfB)
{
    #pragma unroll
    for (int kb = 0; kb < 4; ++kb) {
        zfA[kb] = *(const bf16x8*)&z[(size_t)rowA * HH + kb * 32 + lq * 8];
        zfB[kb] = *(const bf16x8*)&z[(size_t)rowB * HH + kb * 32 + lq * 8];
    }
}

static __device__ __forceinline__ void mlp_pipe(
    const unsigned short* __restrict__ z,
    const __bf16* __restrict__ Wp1, const float* __restrict__ b1,
    const __bf16* __restrict__ Wp2, const float* __restrict__ b2,
    unsigned short* __restrict__ hout, int n)
{
    __shared__ __bf16 Wl1[16384], Wl2[16384];   // 32 KB each
    __shared__ unsigned short tt[8][4096];      // 8 KB per-wave t-tile
    __shared__ float b1l[HH], b2l[HH];

    const int t    = threadIdx.x;               // 0..511
    const int lane = t & 63, wv = t >> 6;
    const int l16  = lane & 15, lq = lane >> 4;
    const int swz  = (l16 & 7) << 4;
    const int ntiles = (n + 255) >> 8;          // 256-node tiles

    #pragma unroll
    for (int i = 0; i < 4; ++i) {
        *(int4*)&Wl1[(i * 512 + t) * 8] = *(const int4*)&Wp1[(i * 512 + t) * 8];
        *(int4*)&Wl2[(i * 512 + t) * 8] = *(const int4*)&Wp2[(i * 512 + t) * 8];
    }
    if (t < HH) b1l[t] = b1[t];
    else if (t < 2 * HH) b2l[t - HH] = b2[t - HH];

    char* tl = (char*)tt[wv];

    int tile = blockIdx.x;
    if (tile >= ntiles) return;

    bf16x8 zfA[4], zfB[4];
    {
        const int r0 = tile * 256 + wv * 32;
        loadz(z, min(r0 + l16, n - 1), min(r0 + 16 + l16, n - 1), lq, zfA, zfB);
    }
    __syncthreads();   // the only barrier: W + biases staged

    while (true) {
        const int r0 = tile * 256 + wv * 32;
        const int nodeA = r0 + l16, nodeB = r0 + 16 + l16;

        // ---- GEMM1: t^T = W1^T @ z^T, streamed per mt into the wave tile
        #pragma unroll
        for (int mt = 0; mt < 8; ++mt) {
            const f32x4 bb = *(const f32x4*)&b1l[mt * 16 + lq * 4];
            f32x4 aA = bb, aB = bb;
            #pragma unroll
            for (int kb = 0; kb < 4; ++kb) {
                const bf16x8 wf = *(const bf16x8*)&Wl1[((mt * 4 + kb) * 64 + lane) * 8];
                aA = __builtin_amdgcn_mfma_f32_16x16x32_bf16(wf, zfA[kb], aA, 0, 0, 0);
                aB = __builtin_amdgcn_mfma_f32_16x16x32_bf16(wf, zfB[kb], aB, 0, 0, 0);
            }
            bf16x4 pa, pb;
            #pragma unroll
            for (int r = 0; r < 4; ++r) {
                pa[r] = (__bf16)fmaxf(aA[r], 0.f);
                pb[r] = (__bf16)fmaxf(aB[r], 0.f);
            }
            *(bf16x4*)(tl + ((l16 * 256 + mt * 32 + lq * 8) ^ swz)) = pa;
            *(bf16x4*)(tl + (((16 + l16) * 256 + mt * 32 + lq * 8) ^ swz)) = pb;
        }

        // ---- prefetch next tile's z (latency hides under GEMM2)
        const int next = tile + gridDim.x;
        bf16x8 nzA[4], nzB[4];
        if (next < ntiles) {
            const int nr0 = next * 256 + wv * 32;
            loadz(z, min(nr0 + l16, n - 1), min(nr0 + 16 + l16, n - 1), lq, nzA, nzB);
        }

        // ---- GEMM2: h^T = W2^T @ t^T (same-wave DS ordering; no barrier)
        bf16x8 tfA[4], tfB[4];
        #pragma unroll
        for (int kb = 0; kb < 4; ++kb) {
            tfA[kb] = *(const bf16x8*)(tl + ((l16 * 256 + kb * 64 + lq * 16) ^ swz));
            tfB[kb] = *(const bf16x8*)(tl + (((16 + l16) * 256 + kb * 64 + lq * 16) ^ swz));
        }
        #pragma unroll
        for (int mb = 0; mb < 8; ++mb) {
            const f32x4 bb = *(const f32x4*)&b2l[mb * 16 + lq * 4];
            f32x4 aA = bb, aB = bb;
            #pragma unroll
            for (int kb = 0; kb < 4; ++kb) {
                const bf16x8 wf = *(const bf16x8*)&Wl2[((mb * 4 + kb) * 64 + lane) * 8];
                aA = __builtin_amdgcn_mfma_f32_16x16x32_bf16(wf, tfA[kb], aA, 0, 0, 0);
                aB = __builtin_amdgcn_mfma_f32_16x16x32_bf16(wf, tfB[kb], aB, 0, 0, 0);
            }
            if (nodeA < n) {
                bf16x4 p;
                #pragma unroll
                for (int r = 0; r < 4; ++r) p[r] = (__bf16)aA[r];
                *(bf16x4*)&hout[(size_t)nodeA * HH + mb * 16 + lq * 4] = p;
            }
            if (nodeB < n) {
                bf16x4 p;
                #pragma unroll
                for (int r = 0; r < 4; ++r) p[r] = (__bf16)aB[r];
                *(bf16x4*)&hout[(size_t)nodeB * HH + mb * 16 + lq * 4] = p;
            }
        }

        if (next >= ntiles) break;
        tile = next;
        #pragma unroll
        for (int kb = 0; kb < 4; ++kb) { zfA[kb] = nzA[kb]; zfB[kb] = nzB[kb]; }
    }
}

__global__ __launch_bounds__(512) void mlp1_k(const unsigned short* z,
                                              const __bf16* Wp1, const float* b1,
                                              const __bf16* Wp2, const float* b2,
                                              unsigned short* h, int n)
{ mlp_pipe(z, Wp1, b1, Wp2, b2, h, n); }

__global__ __launch_bounds__(512) void mlp2_k(const unsigned short* z,
                                              const __bf16* Wp1, const float* b1,
                                              const __bf16* Wp2, const float* b2,
                                              unsigned short* h, int n)
{ mlp_pipe(z, Wp1, b1, Wp2, b2, h, n); }

// ------------------------------------------------------- segment pooling
__global__ __launch_bounds__(64) void pool_k(const unsigned short* __restrict__ h,
                                             const int* __restrict__ bound,
                                             float* __restrict__ pooled)
{
    const int g = blockIdx.x >> 4;            // graph (PSPLIT==16)
    const int s = blockIdx.x & (PSPLIT - 1);  // split
    const int t = threadIdx.x;                // 0..63
    const int half = t >> 5, sl = t & 31;
    const int rb = bound[g], re = bound[g + 1];
    const int len = re - rb;
    const int i0 = rb + (int)(((long)len * s) / PSPLIT);
    const int i1 = rb + (int)(((long)len * (s + 1)) / PSPLIT);
    const uint2* h8 = (const uint2*)h;

    float p0 = 0.f, p1 = 0.f, p2 = 0.f, p3 = 0.f;
    float q0 = 0.f, q1 = 0.f, q2 = 0.f, q3 = 0.f;
    int r = i0 + half;
    for (; r + 2 < i1; r += 4) {
        const uint2 a = h8[(size_t)r * 32 + sl];
        const uint2 b = h8[(size_t)(r + 2) * 32 + sl];
        p0 += bf2f(a.x & 0xffff); p1 += bf2f(a.x >> 16);
        p2 += bf2f(a.y & 0xffff); p3 += bf2f(a.y >> 16);
        q0 += bf2f(b.x & 0xffff); q1 += bf2f(b.x >> 16);
        q2 += bf2f(b.y & 0xffff); q3 += bf2f(b.y >> 16);
    }
    if (r < i1) {
        const uint2 a = h8[(size_t)r * 32 + sl];
        p0 += bf2f(a.x & 0xffff); p1 += bf2f(a.x >> 16);
        p2 += bf2f(a.y & 0xffff); p3 += bf2f(a.y >> 16);
    }
    p0 += q0; p1 += q1; p2 += q2; p3 += q3;
    if (i0 + half < i1) {
        float* p = &pooled[g * HH + sl * 4];
        unsafeAtomicAdd(p + 0, p0);
        unsafeAtomicAdd(p + 1, p1);
        unsafeAtomicAdd(p + 2, p2);
        unsafeAtomicAdd(p + 3, p3);
    }
}

// ---------------------------------------------------------------- final FC
__global__ __launch_bounds__(128) void fc_k(const float* __restrict__ pooled,
                                            const float* __restrict__ Wfc,
                                            const float* __restrict__ bfc,
                                            float* __restrict__ out)
{
    __shared__ float p[HH];
    const int g = blockIdx.x, k = threadIdx.x;
    p[k] = pooled[g * HH + k];
    __syncthreads();
    float acc = bfc[k];
    #pragma unroll 8
    for (int j = 0; j < HH; ++j) acc = fmaf(p[j], Wfc[j * HH + k], acc);
    out[g * HH + k] = acc;
}

extern "C" void kernel_launch(void* const* d_in, const int* in_sizes, int n_in,
                              void* d_out, int out_size, void* d_ws, size_t ws_size,
                              hipStream_t stream)
{
    const float* x     = (const float*)d_in[0];
    const int*   ei    = (const int*)d_in[1];
    const int*   batch = (const int*)d_in[2];
    const float* W1_0 = (const float*)d_in[3];
    const float* b1_0 = (const float*)d_in[4];
    const float* W2_0 = (const float*)d_in[5];
    const float* b2_0 = (const float*)d_in[6];
    const float* W1_1 = (const float*)d_in[7];
    const float* b1_1 = (const float*)d_in[8];
    const float* W2_1 = (const float*)d_in[9];
    const float* b2_1 = (const float*)d_in[10];
    const float* W1_2 = (const float*)d_in[11];
    const float* b1_2 = (const float*)d_in[12];
    const float* W2_2 = (const float*)d_in[13];
    const float* b2_2 = (const float*)d_in[14];
    const float* Wfc  = (const float*)d_in[15];
    const float* bfc  = (const float*)d_in[16];

    const int N = in_sizes[0];          // 100000
    const int E = in_sizes[1] / 2;      // 640000
    const int* src = ei;
    const int* dst = ei + E;

    // ---- workspace carve (256B aligned sections)
    char* p = (char*)d_ws;
    #define CARVE(ty, name, count) ty* name = (ty*)p; p += (((size_t)(count) * sizeof(ty)) + 255) & ~(size_t)255;
    CARVE(unsigned short, hA,     (size_t)N * HH)
    CARVE(unsigned short, hB,     (size_t)N * HH)
    CARVE(float,          pooled, GG * HH)
    CARVE(int,            cnt,    N)
    CARVE(int,            slotbuf,(size_t)N * CAP)
    CARVE(int,            bound,  GG + 1)
    CARVE(__bf16,         Wp,     5 * 16384)
    #undef CARVE
    float* outp = (float*)d_out;

    const int gblk = (N + 127) / 128;      // l0 blocks (782)
    const int zb   = (N + 255) / 256;      // zero blocks (covers pooled too)
    const int ntiles = (N + 255) / 256;    // mlp tiles (391)
    const int mgrid = min(256, ntiles);    // mlp grid (1 block/CU)

    // ---- prep (zero + pack 5 weights + bounds), bucket-CSR fill
    prep_k<<<zb + 41, 256, 0, stream>>>(cnt, pooled, N, W2_0, W1_1, W2_1, W1_2, W2_2,
                                        Wp, batch, bound, zb);
    fill_k<<<(E + 255) / 256, 256, 0, stream>>>(src, dst, cnt, slotbuf, E);

    // ---- layer 0 (x-gather fused; x is tiny/L2-resident)
    l0_k<<<gblk, 256, 0, stream>>>(x, cnt, slotbuf, W1_0, b1_0, Wp, b2_0, hA, N);

    // ---- layer 1
    agg1_k<<<2048, 256, 0, stream>>>(hA, cnt, slotbuf, hB, N);
    mlp1_k<<<mgrid, 512, 0, stream>>>(hB, Wp + 16384, b1_1, Wp + 2 * 16384, b2_1, hA, N);

    // ---- layer 2
    agg2_k<<<2048, 256, 0, stream>>>(hA, cnt, slotbuf, hB, N);
    mlp2_k<<<mgrid, 512, 0, stream>>>(hB, Wp + 3 * 16384, b1_2, Wp + 4 * 16384, b2_2, hA, N);

    // ---- pool + FC
    pool_k<<<GG * PSPLIT, 64, 0, stream>>>(hA, bound, pooled);
    fc_k<<<GG, HH, 0, stream>>>(pooled, Wfc, bfc, outp);
}

// Round 15
// 202.087 us; speedup vs baseline: 1.3901x; 1.3901x over previous
//
#include <hip/hip_runtime.h>

#define HH 128
#define GG 256
#define CAP 32
#define PSPLIT 16

using f32x4  = __attribute__((ext_vector_type(4))) float;
using bf16x4 = __attribute__((ext_vector_type(4))) __bf16;
using bf16x8 = __attribute__((ext_vector_type(8))) __bf16;

static __device__ __forceinline__ float bf2f(unsigned int u) {
    unsigned int x = u << 16;
    return __builtin_bit_cast(float, x);
}
static __device__ __forceinline__ unsigned short f2bf(float f) {
    __bf16 b = (__bf16)f;
    return __builtin_bit_cast(unsigned short, b);
}

// --------------------------------------------- prep: zero + packW x5 + bound
__global__ __launch_bounds__(256) void prep_k(
    int* __restrict__ cnt, float* __restrict__ pooled, int n,
    const float* __restrict__ Wa, const float* __restrict__ Wb,
    const float* __restrict__ Wc, const float* __restrict__ Wd,
    const float* __restrict__ We, __bf16* __restrict__ Wp,
    const int* __restrict__ batch, int* __restrict__ bound, int zb)
{
    const int t = threadIdx.x, b = blockIdx.x;
    if (b < zb) {
        const int i = b * 256 + t;
        if (i < n) cnt[i] = 0;
        if (i < GG * HH) pooled[i] = 0.f;
    } else if (b < zb + 40) {
        const int which = b - zb;
        const int mat = which >> 3;
        const float* W = (mat == 0) ? Wa : (mat == 1) ? Wb : (mat == 2) ? Wc
                       : (mat == 3) ? Wd : We;
        const int slot = (which & 7) * 256 + t;
        const int frag = slot >> 6, lane = slot & 63;
        const int mb = frag >> 2, kb = frag & 3;
        const int col = mb * 16 + (lane & 15);
        const int k0  = kb * 32 + (lane >> 4) * 8;
        bf16x8 v;
        #pragma unroll
        for (int j = 0; j < 8; ++j) v[j] = (__bf16)W[(k0 + j) * HH + col];
        *(bf16x8*)&Wp[(size_t)mat * 16384 + slot * 8] = v;
    } else {
        const int g = t;
        int lo = 0, hi = n;
        while (lo < hi) { int m = (lo + hi) >> 1; if (batch[m] < g) lo = m + 1; else hi = m; }
        bound[g] = lo;
        if (g == 0) bound[GG] = n;
    }
}

// ------------------------------------- bucket-CSR build (single pass)
__global__ __launch_bounds__(256) void fill_k(const int* __restrict__ src,
                                              const int* __restrict__ dst,
                                              int* __restrict__ cnt,
                                              int* __restrict__ slotbuf, int ne)
{
    int e = blockIdx.x * 256 + threadIdx.x;
    if (e < ne) {
        const int d = dst[e];
        const int off = atomicAdd(&cnt[d], 1);
        if (off < CAP) slotbuf[d * CAP + off] = src[e];
    }
}

// ------------------------------------------------- layer 0 (agg + MLP fused)
__global__ __launch_bounds__(256) void l0_k(
    const float* __restrict__ x,
    const int* __restrict__ cnt, const int* __restrict__ slotbuf,
    const float* __restrict__ W1, const float* __restrict__ b1,
    const __bf16* __restrict__ Wp2, const float* __restrict__ b2,
    unsigned short* __restrict__ hout, int n)
{
    __shared__ __bf16 Wl[16384];                // 32 KB W2^T frags
    __shared__ unsigned short tt[4][4096];      // 8 KB per-wave t-tile
    __shared__ float b1l[HH], b2l[HH], w1l[HH];

    const int t    = threadIdx.x;
    const int lane = t & 63, wv = t >> 6;
    const int l16  = lane & 15, lq = lane >> 4;
    const int r0    = blockIdx.x * 128 + wv * 32;
    const int nodeA = r0 + l16, nodeB = r0 + 16 + l16;
    const int rowA  = min(nodeA, n - 1), rowB = min(nodeB, n - 1);
    const int swz   = (l16 & 7) << 4;

    #pragma unroll
    for (int i = 0; i < 8; ++i)
        *(int4*)&Wl[(i * 256 + t) * 8] = *(const int4*)&Wp2[(i * 256 + t) * 8];
    if (t < HH) { b2l[t] = b2[t]; b1l[t] = b1[t]; w1l[t] = W1[t]; }

    // per-lane scalar aggregation of x (masked 4-unroll, no serial tail)
    float sA, sB;
    {
        float s0 = x[rowA], s1 = 0.f, s2 = 0.f, s3 = 0.f;
        const int dA = min(cnt[rowA], CAP);
        const int* sp = &slotbuf[rowA * CAP];
        for (int j = 0; j < dA; j += 4) {
            const int i1 = min(j + 1, dA - 1), i2 = min(j + 2, dA - 1), i3 = min(j + 3, dA - 1);
            const float v0 = x[sp[j]],  v1 = x[sp[i1]];
            const float v2 = x[sp[i2]], v3 = x[sp[i3]];
            s0 += v0;
            s1 += (j + 1 < dA) ? v1 : 0.f;
            s2 += (j + 2 < dA) ? v2 : 0.f;
            s3 += (j + 3 < dA) ? v3 : 0.f;
        }
        sA = (s0 + s1) + (s2 + s3);
        s0 = x[rowB]; s1 = s2 = s3 = 0.f;
        const int dB = min(cnt[rowB], CAP);
        const int* sq = &slotbuf[rowB * CAP];
        for (int j = 0; j < dB; j += 4) {
            const int i1 = min(j + 1, dB - 1), i2 = min(j + 2, dB - 1), i3 = min(j + 3, dB - 1);
            const float v0 = x[sq[j]],  v1 = x[sq[i1]];
            const float v2 = x[sq[i2]], v3 = x[sq[i3]];
            s0 += v0;
            s1 += (j + 1 < dB) ? v1 : 0.f;
            s2 += (j + 2 < dB) ? v2 : 0.f;
            s3 += (j + 3 < dB) ? v3 : 0.f;
        }
        sB = (s0 + s1) + (s2 + s3);
    }
    __syncthreads();   // Wl + biases staged

    char* tl = (char*)tt[wv];
    #pragma unroll
    for (int mt = 0; mt < 8; ++mt) {
        const f32x4 w  = *(const f32x4*)&w1l[mt * 16 + lq * 4];
        const f32x4 bb = *(const f32x4*)&b1l[mt * 16 + lq * 4];
        bf16x4 pa, pb;
        #pragma unroll
        for (int r = 0; r < 4; ++r) {
            pa[r] = (__bf16)fmaxf(fmaf(sA, w[r], bb[r]), 0.f);
            pb[r] = (__bf16)fmaxf(fmaf(sB, w[r], bb[r]), 0.f);
        }
        *(bf16x4*)(tl + ((l16 * 256 + mt * 32 + lq * 8) ^ swz)) = pa;
        *(bf16x4*)(tl + (((16 + l16) * 256 + mt * 32 + lq * 8) ^ swz)) = pb;
    }

    // h^T = W2^T @ t^T (t-tile is wave-private; no barrier needed)
    bf16x8 tfA[4], tfB[4];
    #pragma unroll
    for (int kb = 0; kb < 4; ++kb) {
        tfA[kb] = *(const bf16x8*)(tl + ((l16 * 256 + kb * 64 + lq * 16) ^ swz));
        tfB[kb] = *(const bf16x8*)(tl + (((16 + l16) * 256 + kb * 64 + lq * 16) ^ swz));
    }
    f32x4 a2A[8], a2B[8];
    #pragma unroll
    for (int mb = 0; mb < 8; ++mb) {
        const f32x4 bb = *(const f32x4*)&b2l[mb * 16 + lq * 4];
        a2A[mb] = bb; a2B[mb] = bb;
    }
    #pragma unroll
    for (int mb = 0; mb < 8; ++mb)
        #pragma unroll
        for (int kb = 0; kb < 4; ++kb) {
            const bf16x8 wf = *(const bf16x8*)&Wl[((mb * 4 + kb) * 64 + lane) * 8];
            a2A[mb] = __builtin_amdgcn_mfma_f32_16x16x32_bf16(wf, tfA[kb], a2A[mb], 0, 0, 0);
            a2B[mb] = __builtin_amdgcn_mfma_f32_16x16x32_bf16(wf, tfB[kb], a2B[mb], 0, 0, 0);
        }
    if (nodeA < n) {
        #pragma unroll
        for (int mb = 0; mb < 8; ++mb) {
            bf16x4 p;
            #pragma unroll
            for (int r = 0; r < 4; ++r) p[r] = (__bf16)a2A[mb][r];
            *(bf16x4*)&hout[(size_t)nodeA * HH + mb * 16 + lq * 4] = p;
        }
    }
    if (nodeB < n) {
        #pragma unroll
        for (int mb = 0; mb < 8; ++mb) {
            bf16x4 p;
            #pragma unroll
            for (int r = 0; r < 4; ++r) p[r] = (__bf16)a2B[mb][r];
            *(bf16x4*)&hout[(size_t)nodeB * HH + mb * 16 + lq * 4] = p;
        }
    }
}

// ------------------------------------------- dense pull aggregation (bf16)
static __device__ __forceinline__ void agg_body(
    const unsigned short* __restrict__ h, const int* __restrict__ cnt,
    const int* __restrict__ slotbuf, unsigned short* __restrict__ z, int n)
{
    const int wave = (blockIdx.x * 256 + threadIdx.x) >> 6;
    const int lane = threadIdx.x & 63;
    const int half = lane >> 5, sl = lane & 31;
    const int nw   = (gridDim.x * 256) >> 6;
    const int npairs = (n + 1) >> 1;
    const uint2* h8 = (const uint2*)h;     // 8B = 4 bf16; row = 32 uint2
    uint2* z8 = (uint2*)z;

    for (int pr = wave; pr < npairs; pr += nw) {
        const int node = min(2 * pr + half, n - 1);
        const int deg = min(cnt[node], CAP);
        const int* sp = &slotbuf[node * CAP];
        const uint2 su = h8[(size_t)node * 32 + sl];
        float a0 = bf2f(su.x & 0xffff), a1 = bf2f(su.x >> 16);
        float a2 = bf2f(su.y & 0xffff), a3 = bf2f(su.y >> 16);
        float b0 = 0.f, b1 = 0.f, b2 = 0.f, b3 = 0.f;
        float c0 = 0.f, c1 = 0.f, c2 = 0.f, c3 = 0.f;
        float d0 = 0.f, d1 = 0.f, d2 = 0.f, d3 = 0.f;
        for (int j = 0; j < deg; j += 4) {
            const int i1 = min(j + 1, deg - 1), i2 = min(j + 2, deg - 1), i3 = min(j + 3, deg - 1);
            const uint2 v0 = h8[(size_t)sp[j]  * 32 + sl];
            const uint2 v1 = h8[(size_t)sp[i1] * 32 + sl];
            const uint2 v2 = h8[(size_t)sp[i2] * 32 + sl];
            const uint2 v3 = h8[(size_t)sp[i3] * 32 + sl];
            a0 += bf2f(v0.x & 0xffff); a1 += bf2f(v0.x >> 16);
            a2 += bf2f(v0.y & 0xffff); a3 += bf2f(v0.y >> 16);
            const bool m1 = (j + 1 < deg), m2 = (j + 2 < deg), m3 = (j + 3 < deg);
            b0 += m1 ? bf2f(v1.x & 0xffff) : 0.f; b1 += m1 ? bf2f(v1.x >> 16) : 0.f;
            b2 += m1 ? bf2f(v1.y & 0xffff) : 0.f; b3 += m1 ? bf2f(v1.y >> 16) : 0.f;
            c0 += m2 ? bf2f(v2.x & 0xffff) : 0.f; c1 += m2 ? bf2f(v2.x >> 16) : 0.f;
            c2 += m2 ? bf2f(v2.y & 0xffff) : 0.f; c3 += m2 ? bf2f(v2.y >> 16) : 0.f;
            d0 += m3 ? bf2f(v3.x & 0xffff) : 0.f; d1 += m3 ? bf2f(v3.x >> 16) : 0.f;
            d2 += m3 ? bf2f(v3.y & 0xffff) : 0.f; d3 += m3 ? bf2f(v3.y >> 16) : 0.f;
        }
        const float s0 = (a0 + b0) + (c0 + d0);
        const float s1 = (a1 + b1) + (c1 + d1);
        const float s2 = (a2 + b2) + (c2 + d2);
        const float s3 = (a3 + b3) + (c3 + d3);
        uint2 o;
        o.x = (unsigned int)f2bf(s0) | ((unsigned int)f2bf(s1) << 16);
        o.y = (unsigned int)f2bf(s2) | ((unsigned int)f2bf(s3) << 16);
        z8[(size_t)node * 32 + sl] = o;
    }
}
__global__ __launch_bounds__(256) void agg1_k(const unsigned short* h, const int* cnt,
                                              const int* slotbuf, unsigned short* z, int n)
{ agg_body(h, cnt, slotbuf, z, n); }
__global__ __launch_bounds__(256) void agg2_k(const unsigned short* h, const int* cnt,
                                              const int* slotbuf, unsigned short* z, int n)
{ agg_body(h, cnt, slotbuf, z, n); }

// ------------------------------------------------------------- fused MLP
// h = relu(z @ W1 + b1) @ W2 + b2, transposed MFMA form.
// 512 threads = 8 waves; W1^T AND W2^T both LDS-resident (round-10 proven
// structure, 391 blocks x 1 tile). Single barrier after the W stage; the
// t-tile is wave-private so no fence before GEMM2 (validated r13/r14).
static __device__ __forceinline__ void mlp_body8(
    const unsigned short* __restrict__ z,
    const __bf16* __restrict__ Wp1, const float* __restrict__ b1,
    const __bf16* __restrict__ Wp2, const float* __restrict__ b2,
    unsigned short* __restrict__ hout, int n)
{
    __shared__ __bf16 Wl1[16384], Wl2[16384];   // 32 KB each
    __shared__ unsigned short tt[8][4096];      // 8 KB per-wave t-tile
    __shared__ float b1l[HH], b2l[HH];

    const int t    = threadIdx.x;               // 0..511
    const int lane = t & 63, wv = t >> 6;
    const int l16  = lane & 15, lq = lane >> 4;
    const int r0    = blockIdx.x * 256 + wv * 32;
    const int nodeA = r0 + l16, nodeB = r0 + 16 + l16;
    const int rowA  = min(nodeA, n - 1), rowB = min(nodeB, n - 1);
    const int swz   = (l16 & 7) << 4;

    #pragma unroll
    for (int i = 0; i < 4; ++i) {
        *(int4*)&Wl1[(i * 512 + t) * 8] = *(const int4*)&Wp1[(i * 512 + t) * 8];
        *(int4*)&Wl2[(i * 512 + t) * 8] = *(const int4*)&Wp2[(i * 512 + t) * 8];
    }
    if (t < HH) b1l[t] = b1[t];
    else if (t < 2 * HH) b2l[t - HH] = b2[t - HH];

    // ---- load z fragments (B-operand: col=node, k from lq*8)
    bf16x8 zfA[4], zfB[4];
    #pragma unroll
    for (int kb = 0; kb < 4; ++kb) {
        zfA[kb] = *(const bf16x8*)&z[(size_t)rowA * HH + kb * 32 + lq * 8];
        zfB[kb] = *(const bf16x8*)&z[(size_t)rowB * HH + kb * 32 + lq * 8];
    }
    __syncthreads();   // the only barrier: W + biases staged

    // ---- MFMA1: t^T = W1^T @ z^T
    f32x4 a1A[8], a1B[8];
    #pragma unroll
    for (int mt = 0; mt < 8; ++mt) {
        const f32x4 bb = *(const f32x4*)&b1l[mt * 16 + lq * 4];
        a1A[mt] = bb; a1B[mt] = bb;
    }
    #pragma unroll
    for (int mt = 0; mt < 8; ++mt)
        #pragma unroll
        for (int kb = 0; kb < 4; ++kb) {
            const bf16x8 wf = *(const bf16x8*)&Wl1[((mt * 4 + kb) * 64 + lane) * 8];
            a1A[mt] = __builtin_amdgcn_mfma_f32_16x16x32_bf16(wf, zfA[kb], a1A[mt], 0, 0, 0);
            a1B[mt] = __builtin_amdgcn_mfma_f32_16x16x32_bf16(wf, zfB[kb], a1B[mt], 0, 0, 0);
        }
    char* tl = (char*)tt[wv];
    #pragma unroll
    for (int mt = 0; mt < 8; ++mt) {
        bf16x4 pa, pb;
        #pragma unroll
        for (int r = 0; r < 4; ++r) {
            pa[r] = (__bf16)fmaxf(a1A[mt][r], 0.f);
            pb[r] = (__bf16)fmaxf(a1B[mt][r], 0.f);
        }
        *(bf16x4*)(tl + ((l16 * 256 + mt * 32 + lq * 8) ^ swz)) = pa;
        *(bf16x4*)(tl + (((16 + l16) * 256 + mt * 32 + lq * 8) ^ swz)) = pb;
    }

    // ---- MFMA2: h^T = W2^T @ t^T (wave-private tile; per-wave DS ordering)
    bf16x8 tfA[4], tfB[4];
    #pragma unroll
    for (int kb = 0; kb < 4; ++kb) {
        tfA[kb] = *(const bf16x8*)(tl + ((l16 * 256 + kb * 64 + lq * 16) ^ swz));
        tfB[kb] = *(const bf16x8*)(tl + (((16 + l16) * 256 + kb * 64 + lq * 16) ^ swz));
    }
    f32x4 a2A[8], a2B[8];
    #pragma unroll
    for (int mb = 0; mb < 8; ++mb) {
        const f32x4 bb = *(const f32x4*)&b2l[mb * 16 + lq * 4];
        a2A[mb] = bb; a2B[mb] = bb;
    }
    #pragma unroll
    for (int mb = 0; mb < 8; ++mb)
        #pragma unroll
        for (int kb = 0; kb < 4; ++kb) {
            const bf16x8 wf = *(const bf16x8*)&Wl2[((mb * 4 + kb) * 64 + lane) * 8];
            a2A[mb] = __builtin_amdgcn_mfma_f32_16x16x32_bf16(wf, tfA[kb], a2A[mb], 0, 0, 0);
            a2B[mb] = __builtin_amdgcn_mfma_f32_16x16x32_bf16(wf, tfB[kb], a2B[mb], 0, 0, 0);
        }

    if (nodeA < n) {
        #pragma unroll
        for (int mb = 0; mb < 8; ++mb) {
            bf16x4 p;
            #pragma unroll
            for (int r = 0; r < 4; ++r) p[r] = (__bf16)a2A[mb][r];
            *(bf16x4*)&hout[(size_t)nodeA * HH + mb * 16 + lq * 4] = p;
        }
    }
    if (nodeB < n) {
        #pragma unroll
        for (int mb = 0; mb < 8; ++mb) {
            bf16x4 p;
            #pragma unroll
            for (int r = 0; r < 4; ++r) p[r] = (__bf16)a2B[mb][r];
            *(bf16x4*)&hout[(size_t)nodeB * HH + mb * 16 + lq * 4] = p;
        }
    }
}

__global__ __launch_bounds__(512) void mlp1_k(const unsigned short* z,
                                              const __bf16* Wp1, const float* b1,
                                              const __bf16* Wp2, const float* b2,
                                              unsigned short* h, int n)
{ mlp_body8(z, Wp1, b1, Wp2, b2, h, n); }

__global__ __launch_bounds__(512) void mlp2_k(const unsigned short* z,
                                              const __bf16* Wp1, const float* b1,
                                              const __bf16* Wp2, const float* b2,
                                              unsigned short* h, int n)
{ mlp_body8(z, Wp1, b1, Wp2, b2, h, n); }

// ------------------------------------------------------- segment pooling
__global__ __launch_bounds__(64) void pool_k(const unsigned short* __restrict__ h,
                                             const int* __restrict__ bound,
                                             float* __restrict__ pooled)
{
    const int g = blockIdx.x >> 4;            // graph (PSPLIT==16)
    const int s = blockIdx.x & (PSPLIT - 1);  // split
    const int t = threadIdx.x;                // 0..63
    const int half = t >> 5, sl = t & 31;
    const int rb = bound[g], re = bound[g + 1];
    const int len = re - rb;
    const int i0 = rb + (int)(((long)len * s) / PSPLIT);
    const int i1 = rb + (int)(((long)len * (s + 1)) / PSPLIT);
    const uint2* h8 = (const uint2*)h;

    float p0 = 0.f, p1 = 0.f, p2 = 0.f, p3 = 0.f;
    float q0 = 0.f, q1 = 0.f, q2 = 0.f, q3 = 0.f;
    int r = i0 + half;
    for (; r + 2 < i1; r += 4) {
        const uint2 a = h8[(size_t)r * 32 + sl];
        const uint2 b = h8[(size_t)(r + 2) * 32 + sl];
        p0 += bf2f(a.x & 0xffff); p1 += bf2f(a.x >> 16);
        p2 += bf2f(a.y & 0xffff); p3 += bf2f(a.y >> 16);
        q0 += bf2f(b.x & 0xffff); q1 += bf2f(b.x >> 16);
        q2 += bf2f(b.y & 0xffff); q3 += bf2f(b.y >> 16);
    }
    if (r < i1) {
        const uint2 a = h8[(size_t)r * 32 + sl];
        p0 += bf2f(a.x & 0xffff); p1 += bf2f(a.x >> 16);
        p2 += bf2f(a.y & 0xffff); p3 += bf2f(a.y >> 16);
    }
    p0 += q0; p1 += q1; p2 += q2; p3 += q3;
    if (i0 + half < i1) {
        float* p = &pooled[g * HH + sl * 4];
        unsafeAtomicAdd(p + 0, p0);
        unsafeAtomicAdd(p + 1, p1);
        unsafeAtomicAdd(p + 2, p2);
        unsafeAtomicAdd(p + 3, p3);
    }
}

// ---------------------------------------------------------------- final FC
__global__ __launch_bounds__(128) void fc_k(const float* __restrict__ pooled,
                                            const float* __restrict__ Wfc,
                                            const float* __restrict__ bfc,
                                            float* __restrict__ out)
{
    __shared__ float p[HH];
    const int g = blockIdx.x, k = threadIdx.x;
    p[k] = pooled[g * HH + k];
    __syncthreads();
    float acc = bfc[k];
    #pragma unroll 8
    for (int j = 0; j < HH; ++j) acc = fmaf(p[j], Wfc[j * HH + k], acc);
    out[g * HH + k] = acc;
}

extern "C" void kernel_launch(void* const* d_in, const int* in_sizes, int n_in,
                              void* d_out, int out_size, void* d_ws, size_t ws_size,
                              hipStream_t stream)
{
    const float* x     = (const float*)d_in[0];
    const int*   ei    = (const int*)d_in[1];
    const int*   batch = (const int*)d_in[2];
    const float* W1_0 = (const float*)d_in[3];
    const float* b1_0 = (const float*)d_in[4];
    const float* W2_0 = (const float*)d_in[5];
    const float* b2_0 = (const float*)d_in[6];
    const float* W1_1 = (const float*)d_in[7];
    const float* b1_1 = (const float*)d_in[8];
    const float* W2_1 = (const float*)d_in[9];
    const float* b2_1 = (const float*)d_in[10];
    const float* W1_2 = (const float*)d_in[11];
    const float* b1_2 = (const float*)d_in[12];
    const float* W2_2 = (const float*)d_in[13];
    const float* b2_2 = (const float*)d_in[14];
    const float* Wfc  = (const float*)d_in[15];
    const float* bfc  = (const float*)d_in[16];

    const int N = in_sizes[0];          // 100000
    const int E = in_sizes[1] / 2;      // 640000
    const int* src = ei;
    const int* dst = ei + E;

    // ---- workspace carve (256B aligned sections)
    char* p = (char*)d_ws;
    #define CARVE(ty, name, count) ty* name = (ty*)p; p += (((size_t)(count) * sizeof(ty)) + 255) & ~(size_t)255;
    CARVE(unsigned short, hA,     (size_t)N * HH)
    CARVE(unsigned short, hB,     (size_t)N * HH)
    CARVE(float,          pooled, GG * HH)
    CARVE(int,            cnt,    N)
    CARVE(int,            slotbuf,(size_t)N * CAP)
    CARVE(int,            bound,  GG + 1)
    CARVE(__bf16,         Wp,     5 * 16384)
    #undef CARVE
    float* outp = (float*)d_out;

    const int gblk  = (N + 127) / 128;     // l0 blocks (782)
    const int gblk8 = (N + 255) / 256;     // mlp blocks (391)
    const int zb    = (N + 255) / 256;     // zero blocks (covers pooled too)

    // ---- prep (zero + pack 5 weights + bounds), bucket-CSR fill
    prep_k<<<zb + 41, 256, 0, stream>>>(cnt, pooled, N, W2_0, W1_1, W2_1, W1_2, W2_2,
                                        Wp, batch, bound, zb);
    fill_k<<<(E + 255) / 256, 256, 0, stream>>>(src, dst, cnt, slotbuf, E);

    // ---- layer 0 (x-gather fused; x is tiny/L2-resident)
    l0_k<<<gblk, 256, 0, stream>>>(x, cnt, slotbuf, W1_0, b1_0, Wp, b2_0, hA, N);

    // ---- layer 1
    agg1_k<<<2048, 256, 0, stream>>>(hA, cnt, slotbuf, hB, N);
    mlp1_k<<<gblk8, 512, 0, stream>>>(hB, Wp + 16384, b1_1, Wp + 2 * 16384, b2_1, hA, N);

    // ---- layer 2
    agg2_k<<<2048, 256, 0, stream>>>(hA, cnt, slotbuf, hB, N);
    mlp2_k<<<gblk8, 512, 0, stream>>>(hB, Wp + 3 * 16384, b1_2, Wp + 4 * 16384, b2_2, hA, N);

    // ---- pool + FC
    pool_k<<<GG * PSPLIT, 64, 0, stream>>>(hA, bound, pooled);
    fc_k<<<GG, HH, 0, stream>>>(pooled, Wfc, bfc, outp);
}